// Round 15
// baseline (284.073 us; speedup 1.0000x reference)
//
#include <hip/hip_runtime.h>
#include <hip/hip_fp16.h>

#define NPIX 65536
#define WIMG 256
#define HIMG 256
#define TW 16
#define TH 8
#define HSTR 24      // halo row stride (halves): 10 rows x 24, 18 used per row
#define NSLOT 240
#define YCH 248      // ys per-channel stride (halves)

typedef __attribute__((ext_vector_type(8))) _Float16 half8;
typedef __attribute__((ext_vector_type(4))) float f32x4;

__device__ __forceinline__ unsigned int h2u(__half2 h) {
  union { __half2 h; unsigned int u; } c; c.h = h; return c.u;
}
__device__ __forceinline__ __half2 u2h(unsigned int u) {
  union { unsigned int u; __half2 h; } c; c.u = u; return c.h;
}
__device__ __forceinline__ __half2 sp2(_Float16 s) {
  union { _Float16 h[2]; __half2 v; } u; u.h[0] = s; u.h[1] = s; return u.v;
}
// q/k layout: [ch][px 0..127] swizzled; pxblk = px>>3
__device__ __forceinline__ int qk_idx(int ch, int pxblk) {
  return ch * 128 + ((pxblk ^ (ch & 7)) << 3);
}
__device__ __forceinline__ void ld16_lds(const void* g, void* l) {
  __builtin_amdgcn_global_load_lds(
      (const __attribute__((address_space(1))) unsigned int*)g,
      (__attribute__((address_space(3))) unsigned int*)l, 16, 0, 0);
}

// fused: zero accumulators (6144 f32) + weight fp16 pre-pack
__global__ __launch_bounds__(256)
void k_prep(const float* __restrict__ wq1, const float* __restrict__ wq2,
            const float* __restrict__ wd1, const float* __restrict__ wd2,
            float* __restrict__ zbuf,
            _Float16* __restrict__ wqh, _Float16* __restrict__ wdh) {
  int i = blockIdx.x * 256 + threadIdx.x;
  if (i < 6144) {
    zbuf[i] = 0.0f;
  } else {
    int j = i - 6144;
    if (j < 24576) {
      int br = j / 12288, r = j - br * 12288;
      wqh[j] = (_Float16)((br ? wq2 : wq1)[r]);
    } else {
      int k = j - 24576;
      int br = k / 3072, r = k - br * 3072;
      int o = r >> 4, t = r & 15;
      wdh[k] = (t < 9) ? (_Float16)((br ? wd2 : wd1)[o * 9 + t]) : (_Float16)0.0f;
    }
  }
}

// r13 structure (measured optimum) with direct-from-x staging (k_xt eliminated):
// thread (chunk=lane&7, srow=lane>>3) loads 8 f32 (one chunk of one slot),
// packs half8, writes b128 at chunk-XOR position -> layout identical to DMA path.
__global__ __launch_bounds__(256, 3)
void k_qkv(const float* __restrict__ x,
           const _Float16* __restrict__ wqh, const _Float16* __restrict__ wdh,
           __half* __restrict__ vbuf, float* __restrict__ gram,
           float* __restrict__ sqq, float* __restrict__ sqk)
{
  __shared__ __align__(16) _Float16 xs[256 * 64];   // 32768 B; reused as q/k
  __shared__ __align__(16) _Float16 ys[32 * YCH];   // 15872 B

  const int tid = threadIdx.x;
  const int lane = tid & 63;
  const int wid = tid >> 6;
  const int tile = blockIdx.x;
  const int br = blockIdx.y;
  const int b = blockIdx.z;
  const int tx0 = (tile & 15) * TW;
  const int ty0 = (tile >> 4) * TH;

  const _Float16* wqb = wqh + br * 12288;
  const _Float16* wdb = wdh + br * 3072;
  const float* xb = x + ((size_t)b * 128 + br * 64) * NPIX;

  // ---- staging: f32 x -> fp16 xs[slot][c] chunk-swizzled, b128 writes ----
  {
    const int schunk = lane & 7, srow = lane >> 3;
    #pragma unroll
    for (int i = 0; i < 8; ++i) {
      int s = (i * 4 + wid) * 8 + srow;
      if (s < NSLOT) {
        int hy = s / HSTR, hx = s - hy * HSTR;
        int gy = ty0 - 1 + hy, gx = tx0 - 1 + hx;
        bool valid = (hx < 18) && ((unsigned)gy < HIMG) && ((unsigned)gx < WIMG);
        int gyc = min(max(gy, 0), HIMG - 1);
        int gxc = min(max(gx, 0), WIMG - 1);
        const float* xp = xb + (size_t)(schunk * 8) * NPIX + gyc * WIMG + gxc;
        half8 h;
        #pragma unroll
        for (int e = 0; e < 8; ++e) {
          float v = xp[(size_t)e * NPIX];
          h[e] = valid ? (_Float16)v : (_Float16)0.0f;
        }
        *(half8*)(xs + s * 64 + ((schunk ^ srow) << 3)) = h;
      }
    }
  }
  __syncthreads();

  const int col = lane & 15;
  const int qrow = lane >> 4;          // 0..3
  const int oo = tid >> 3;             // dw unit: 0..31
  const int row = tid & 7;

  unsigned int qreg[2][8], kreg[2][8]; // static-indexed (h,k2 unrolled)

  // parts: p=0 -> q, p=1 -> k, p=2 -> v
  #pragma unroll
  for (int p = 0; p < 3; ++p) {
    #pragma unroll
    for (int h = 0; h < 2; ++h) {
      // ---- pointwise weight B-fragments (fp16 direct) ----
      half8 wf[2][2];
      #pragma unroll
      for (int nt = 0; nt < 2; ++nt)
        #pragma unroll
        for (int kc = 0; kc < 2; ++kc)
          wf[kc][nt] = *(const half8*)(wqb
              + (((p * 64 + h * 32 + nt * 16 + col) << 6) + kc * 32 + qrow * 8));

      // ---- pointwise via MFMA: y[o'][px] for o' in [0,32) ----
      for (int mt = wid; mt < 15; mt += 4) {
        int px = mt * 16 + col;
        half8 af0 = *(const half8*)(xs + px * 64 + (((qrow    ) ^ (px & 7)) << 3));
        half8 af1 = *(const half8*)(xs + px * 64 + (((4 + qrow) ^ (px & 7)) << 3));
        f32x4 a0 = {0,0,0,0}, a1 = {0,0,0,0};
        a0 = __builtin_amdgcn_mfma_f32_16x16x32_f16(af0, wf[0][0], a0, 0, 0, 0);
        a0 = __builtin_amdgcn_mfma_f32_16x16x32_f16(af1, wf[1][0], a0, 0, 0, 0);
        a1 = __builtin_amdgcn_mfma_f32_16x16x32_f16(af0, wf[0][1], a1, 0, 0, 0);
        a1 = __builtin_amdgcn_mfma_f32_16x16x32_f16(af1, wf[1][1], a1, 0, 0, 0);
        int pxd = mt * 16 + qrow * 4;
        __half2* d0 = (__half2*)(ys + (col     ) * YCH + pxd);
        __half2* d1 = (__half2*)(ys + (col + 16) * YCH + pxd);
        d0[0] = __floats2half2_rn(a0[0], a0[1]);
        d0[1] = __floats2half2_rn(a0[2], a0[3]);
        d1[0] = __floats2half2_rn(a1[0], a1[1]);
        d1[1] = __floats2half2_rn(a1[2], a1[3]);
      }
      __syncthreads();

      // ---- depthwise 3x3 for o = h*32+oo, one 16-px row per thread ----
      {
        const int o = h * 32 + oo;
        const _Float16* wdp = wdb + ((p * 64 + o) << 4);
        half8 wv = *(const half8*)wdp;
        _Float16 w8v = wdp[8];
        __half2 w2[9];
        #pragma unroll
        for (int j = 0; j < 8; ++j) w2[j] = sp2(wv[j]);
        w2[8] = sp2(w8v);
        __half2 a[8];
        #pragma unroll
        for (int k2 = 0; k2 < 8; ++k2) a[k2] = u2h(0u);
        #pragma unroll
        for (int ky = 0; ky < 3; ++ky) {
          const _Float16* rp = ys + oo * YCH + (row + ky) * HSTR;
          uint4 ra = *(const uint4*)rp;
          uint4 rb = *(const uint4*)(rp + 8);
          unsigned int rc = *(const unsigned int*)(rp + 16);
          unsigned int A[9] = {ra.x, ra.y, ra.z, ra.w, rb.x, rb.y, rb.z, rb.w, rc};
          #pragma unroll
          for (int k2 = 0; k2 < 8; ++k2) {
            unsigned int M = (A[k2] >> 16) | (A[k2 + 1] << 16);
            a[k2] = __hfma2(w2[ky * 3 + 0], u2h(A[k2]), a[k2]);
            a[k2] = __hfma2(w2[ky * 3 + 1], u2h(M), a[k2]);
            a[k2] = __hfma2(w2[ky * 3 + 2], u2h(A[k2 + 1]), a[k2]);
          }
        }
        if (p == 0) {
          #pragma unroll
          for (int k2 = 0; k2 < 8; ++k2) qreg[h][k2] = h2u(a[k2]);
        } else if (p == 1) {
          #pragma unroll
          for (int k2 = 0; k2 < 8; ++k2) kreg[h][k2] = h2u(a[k2]);
        } else {
          __half* vrow = (__half*)(vbuf
              + ((size_t)((br * 4 + b) * 64 + o)) * NPIX
              + (ty0 + row) * WIMG + tx0);
          uint4 s0 = {h2u(a[0]), h2u(a[1]), h2u(a[2]), h2u(a[3])};
          uint4 s1 = {h2u(a[4]), h2u(a[5]), h2u(a[6]), h2u(a[7])};
          *(uint4*)vrow = s0;
          *(uint4*)(vrow + 8) = s1;
          if (h == 1) {
            _Float16* qsb = xs;
            _Float16* ksb = xs + 64 * 128;
            #pragma unroll
            for (int hh = 0; hh < 2; ++hh) {
              int ch = hh * 32 + oo;
              uint4 q0 = {qreg[hh][0], qreg[hh][1], qreg[hh][2], qreg[hh][3]};
              uint4 q1 = {qreg[hh][4], qreg[hh][5], qreg[hh][6], qreg[hh][7]};
              uint4 k0 = {kreg[hh][0], kreg[hh][1], kreg[hh][2], kreg[hh][3]};
              uint4 k1 = {kreg[hh][4], kreg[hh][5], kreg[hh][6], kreg[hh][7]};
              *(uint4*)(qsb + qk_idx(ch, 2 * row))     = q0;
              *(uint4*)(qsb + qk_idx(ch, 2 * row + 1)) = q1;
              *(uint4*)(ksb + qk_idx(ch, 2 * row))     = k0;
              *(uint4*)(ksb + qk_idx(ch, 2 * row + 1)) = k1;
            }
          }
        }
      }
      __syncthreads();
    }
  }

  // ---- gram: qk + qq + kk diag head-tiles via MFMA, K=128 px ----
  {
    const _Float16* qsb = xs;
    const _Float16* ksb = xs + 64 * 128;
    f32x4 gqk = {0,0,0,0}, gqq = {0,0,0,0}, gkk = {0,0,0,0};
    int ch = wid * 16 + col;
    #pragma unroll
    for (int kc = 0; kc < 4; ++kc) {
      int pb = kc * 4 + qrow;
      half8 aq = *(const half8*)(qsb + qk_idx(ch, pb));
      half8 bk = *(const half8*)(ksb + qk_idx(ch, pb));
      gqk = __builtin_amdgcn_mfma_f32_16x16x32_f16(aq, bk, gqk, 0, 0, 0);
      gqq = __builtin_amdgcn_mfma_f32_16x16x32_f16(aq, aq, gqq, 0, 0, 0);
      gkk = __builtin_amdgcn_mfma_f32_16x16x32_f16(bk, bk, gkk, 0, 0, 0);
    }
    const int gb_off = (br * 4 + b);
    if (((lane >> 3) & 1) == (lane >> 5)) {
      float* gb = gram + gb_off * 512;
      int kch = ch;
      int qc0 = wid * 16 + qrow * 4;
      #pragma unroll
      for (int r = 0; r < 4; ++r) {
        int qch = qc0 + r;
        atomicAdd(&gb[(qch >> 3) * 64 + (qch & 7) * 8 + (kch & 7)], gqk[r]);
      }
    }
    if ((col >> 2) == qrow) {   // diagonal lanes
      atomicAdd(&sqq[gb_off * 64 + ch], gqq[lane & 3]);
      atomicAdd(&sqk[gb_off * 64 + ch], gkk[lane & 3]);
    }
  }
}

// softmax(G scaled) -> attn, Weff^T = (w_po @ blockdiag(attn))^T stored fp16 [o][c]
__global__ __launch_bounds__(64)
void k_attn(const float* __restrict__ gram, const float* __restrict__ sqq,
            const float* __restrict__ sqk,
            const float* __restrict__ wpo1, const float* __restrict__ wpo2,
            const float* __restrict__ t1, const float* __restrict__ t2,
            _Float16* __restrict__ wefft)
{
  const int br = blockIdx.x, b = blockIdx.y;
  const int t = threadIdx.x;
  __shared__ float attn[8][8][8];
  const float* gb = gram + (br * 4 + b) * 512;
  const float* sq = sqq + (br * 4 + b) * 64;
  const float* sk = sqk + (br * 4 + b) * 64;
  const float* tt = br ? t2 : t1;
  {
    int h = t >> 3, cq = t & 7;
    float ts = tt[h];
    float qn = fmaxf(sqrtf(sq[h * 8 + cq]), 1e-12f);
    float lg[8], m = -1e30f;
    #pragma unroll
    for (int d2 = 0; d2 < 8; ++d2) {
      float kn = fmaxf(sqrtf(sk[h * 8 + d2]), 1e-12f);
      lg[d2] = ts * gb[h * 64 + cq * 8 + d2] / (qn * kn);
      m = fmaxf(m, lg[d2]);
    }
    float s = 0.f;
    #pragma unroll
    for (int d2 = 0; d2 < 8; ++d2) { lg[d2] = expf(lg[d2] - m); s += lg[d2]; }
    float inv = 1.0f / s;
    #pragma unroll
    for (int d2 = 0; d2 < 8; ++d2) attn[h][cq][d2] = lg[d2] * inv;
  }
  __syncthreads();
  const float* wpo = br ? wpo2 : wpo1;
  _Float16* wt = wefft + (br * 4 + b) * 4096;
  for (int cp = 0; cp < 64; ++cp) {
    int hp = cp >> 3, ip = cp & 7;
    float acc = 0.f;
    #pragma unroll
    for (int j = 0; j < 8; ++j)
      acc += wpo[t * 64 + hp * 8 + j] * attn[hp][j][ip];
    wt[t * 64 + cp] = (_Float16)acc;   // [o][c]
  }
}

// out[b, obr*64+o2, px] = sum_c Weff[c][o2] * v[1-obr][b][c][px]  via MFMA
__global__ __launch_bounds__(256)
void k_out(const __half* __restrict__ vbuf, const _Float16* __restrict__ wefft,
           float* __restrict__ out)
{
  __shared__ __align__(16) _Float16 vs[64 * 128];   // 16384 B [c][px]
  __shared__ __align__(16) _Float16 vt[128 * 64];   // 16384 B [px][c] swizzled

  const int strip = blockIdx.x;        // 0..511, 128 px each
  const int obr = blockIdx.y, b = blockIdx.z;
  const int brv = 1 - obr;
  const int tid = threadIdx.x;
  const int lane = tid & 63;
  const int wid = tid >> 6;
  const int col = lane & 15;
  const int qrow = lane >> 4;

  const __half* vb = vbuf + ((size_t)(brv * 4 + b) * 64) * NPIX + strip * 128;

  for (int i = 0; i < 4; ++i) {
    int it = wid * 4 + i;
    const void* src = (const void*)((const _Float16*)vb
        + (size_t)(it * 4 + (lane >> 4)) * NPIX + (lane & 15) * 8);
    ld16_lds(src, (void*)(vs + it * 512));
  }
  asm volatile("s_waitcnt vmcnt(0)" ::: "memory");
  __syncthreads();

  {
    int px = tid & 127, cb = tid >> 7;
    #pragma unroll
    for (int j = 0; j < 4; ++j) {
      half8 h;
      #pragma unroll
      for (int e = 0; e < 8; ++e) h[e] = vs[(cb * 32 + j * 8 + e) * 128 + px];
      int chunk = cb * 4 + j;
      *(half8*)(vt + ((px * 8 + (chunk ^ (px & 7))) << 3)) = h;
    }
  }
  __syncthreads();

  const _Float16* wt = wefft + (obr * 4 + b) * 4096;
  half8 bf[2][4];
  #pragma unroll
  for (int nt = 0; nt < 4; ++nt)
    #pragma unroll
    for (int kc = 0; kc < 2; ++kc)
      bf[kc][nt] = *(const half8*)(wt + (nt * 16 + col) * 64 + kc * 32 + qrow * 8);

  float* ob = out + ((size_t)b * 128 + obr * 64) * NPIX + strip * 128;
  #pragma unroll
  for (int mi = 0; mi < 2; ++mi) {
    int mt = wid * 2 + mi;
    int px = mt * 16 + col;
    half8 af0 = *(const half8*)(vt + ((px * 8 + ((qrow    ) ^ (px & 7))) << 3));
    half8 af1 = *(const half8*)(vt + ((px * 8 + ((4 + qrow) ^ (px & 7))) << 3));
    f32x4 acc[4] = {{0,0,0,0},{0,0,0,0},{0,0,0,0},{0,0,0,0}};
    #pragma unroll
    for (int nt = 0; nt < 4; ++nt) {
      acc[nt] = __builtin_amdgcn_mfma_f32_16x16x32_f16(af0, bf[0][nt], acc[nt], 0, 0, 0);
      acc[nt] = __builtin_amdgcn_mfma_f32_16x16x32_f16(af1, bf[1][nt], acc[nt], 0, 0, 0);
    }
    int pxd = mt * 16 + qrow * 4;
    #pragma unroll
    for (int nt = 0; nt < 4; ++nt) {
      float4 s = {acc[nt][0], acc[nt][1], acc[nt][2], acc[nt][3]};
      *(float4*)(ob + (size_t)(nt * 16 + col) * NPIX + pxd) = s;
    }
  }
}

extern "C" void kernel_launch(void* const* d_in, const int* in_sizes, int n_in,
                              void* d_out, int out_size, void* d_ws, size_t ws_size,
                              hipStream_t stream) {
  const float* x     = (const float*)d_in[0];
  const float* wqkv1 = (const float*)d_in[1];
  const float* wqkv2 = (const float*)d_in[2];
  const float* wdw1  = (const float*)d_in[3];
  const float* wdw2  = (const float*)d_in[4];
  const float* wpo1  = (const float*)d_in[5];
  const float* wpo2  = (const float*)d_in[6];
  const float* t1    = (const float*)d_in[7];
  const float* t2    = (const float*)d_in[8];

  char* ws = (char*)d_ws;
  __half* vbuf = (__half*)ws;                     // 67,108,864 B
  float* gram  = (float*)(ws + 67108864);         // 4096 f32
  float* sqq   = gram + 4096;                     // 512
  float* sqk   = sqq + 512;                       // 512
  float* zpad  = sqk + 512;                       // 1024 f32 (part of zeroed block)
  _Float16* wqkvh = (_Float16*)(zpad + 1024);     // 2*12288 halves
  _Float16* wdwh  = wqkvh + 24576;                // 2*3072 halves
  _Float16* wefft = wdwh + 6144;                  // 2*4*4096 halves

  k_prep<<<dim3(144), dim3(256), 0, stream>>>(wqkv1, wqkv2, wdw1, wdw2,
                                              gram, wqkvh, wdwh);
  k_qkv<<<dim3(512, 2, 4), dim3(256), 0, stream>>>(x, wqkvh, wdwh,
                                                   vbuf, gram, sqq, sqk);
  k_attn<<<dim3(2, 4), dim3(64), 0, stream>>>(gram, sqq, sqk, wpo1, wpo2, t1, t2, wefft);
  k_out<<<dim3(512, 2, 4), dim3(256), 0, stream>>>(vbuf, wefft, (float*)d_out);
}

// Round 16
// 240.933 us; speedup vs baseline: 1.1791x; 1.1791x over previous
//
#include <hip/hip_runtime.h>
#include <hip/hip_fp16.h>

#define NPIX 65536
#define WIMG 256
#define HIMG 256
#define TW 16
#define TH 8
#define HSTR 24      // halo row stride (halves): 10 rows x 24, 18 used per row
#define NSLOT 240
#define YCH 248      // ys per-channel stride (halves)

typedef __attribute__((ext_vector_type(8))) _Float16 half8;
typedef __attribute__((ext_vector_type(4))) float f32x4;

__device__ __forceinline__ unsigned int h2u(__half2 h) {
  union { __half2 h; unsigned int u; } c; c.h = h; return c.u;
}
__device__ __forceinline__ __half2 u2h(unsigned int u) {
  union { unsigned int u; __half2 h; } c; c.u = u; return c.h;
}
__device__ __forceinline__ __half2 sp2(_Float16 s) {
  union { _Float16 h[2]; __half2 v; } u; u.h[0] = s; u.h[1] = s; return u.v;
}
// q/k layout: [ch][px 0..127] swizzled; pxblk = px>>3
__device__ __forceinline__ int qk_idx(int ch, int pxblk) {
  return ch * 128 + ((pxblk ^ (ch & 7)) << 3);
}
__device__ __forceinline__ void ld16_lds(const void* g, void* l) {
  __builtin_amdgcn_global_load_lds(
      (const __attribute__((address_space(1))) unsigned int*)g,
      (__attribute__((address_space(3))) unsigned int*)l, 16, 0, 0);
}

// fused: zero accumulators (6144 f32) + weight fp16 pre-pack
__global__ __launch_bounds__(256)
void k_prep(const float* __restrict__ wq1, const float* __restrict__ wq2,
            const float* __restrict__ wd1, const float* __restrict__ wd2,
            float* __restrict__ zbuf,
            _Float16* __restrict__ wqh, _Float16* __restrict__ wdh) {
  int i = blockIdx.x * 256 + threadIdx.x;
  if (i < 6144) {
    zbuf[i] = 0.0f;
  } else {
    int j = i - 6144;
    if (j < 24576) {
      int br = j / 12288, r = j - br * 12288;
      wqh[j] = (_Float16)((br ? wq2 : wq1)[r]);
    } else {
      int k = j - 24576;
      int br = k / 3072, r = k - br * 3072;
      int o = r >> 4, t = r & 15;
      wdh[k] = (t < 9) ? (_Float16)((br ? wd2 : wd1)[o * 9 + t]) : (_Float16)0.0f;
    }
  }
}

// x f32 [b][128c][px] -> xT fp16 [b*2+br][px][c64]
__global__ __launch_bounds__(256)
void k_xt(const float* __restrict__ x, __half* __restrict__ xT) {
  __shared__ _Float16 tile[64 * 257];
  const int strip = blockIdx.x;
  const int br = blockIdx.y, b = blockIdx.z;
  const int tid = threadIdx.x;
  const float* xb = x + ((size_t)b * 128 + br * 64) * NPIX + strip * 256;
  #pragma unroll 8
  for (int c = 0; c < 64; ++c)
    tile[c * 257 + tid] = (_Float16)xb[(size_t)c * NPIX + tid];
  __syncthreads();
  __half* xo = xT + ((size_t)(b * 2 + br) * NPIX + strip * 256) * 64;
  const int j = tid & 7;
  #pragma unroll
  for (int i = 0; i < 8; ++i) {
    int p = (tid >> 3) + i * 32;
    half8 h;
    #pragma unroll
    for (int k = 0; k < 8; ++k) h[k] = tile[(j * 8 + k) * 257 + p];
    *(half8*)((_Float16*)xo + p * 64 + j * 8) = h;
  }
}

// r13 structure with 16-ch phases + single ys buffer: LDS 40704B -> 4 blocks/CU.
__global__ __launch_bounds__(256, 4)
void k_qkv(const __half* __restrict__ xT,
           const _Float16* __restrict__ wqh, const _Float16* __restrict__ wdh,
           const float* __restrict__ zpage,
           __half* __restrict__ vbuf, float* __restrict__ gram,
           float* __restrict__ sqq, float* __restrict__ sqk)
{
  __shared__ __align__(16) _Float16 xs[256 * 64];   // 32768 B; reused as q/k
  __shared__ __align__(16) _Float16 ys[16 * YCH];   // 7936 B

  const int tid = threadIdx.x;
  const int lane = tid & 63;
  const int wid = tid >> 6;
  const int tile = blockIdx.x;
  const int br = blockIdx.y;
  const int b = blockIdx.z;
  const int tx0 = (tile & 15) * TW;
  const int ty0 = (tile >> 4) * TH;

  const _Float16* wqb = wqh + br * 12288;
  const _Float16* wdb = wdh + br * 3072;
  const __half* xTimg = xT + (size_t)(b * 2 + br) * NPIX * 64;

  // ---- async DMA staging: 30 x 1KB, source-swizzled, LDS linear ----
  {
    const int j = lane & 7, pl = lane >> 3;
    for (int it = wid; it < 30; it += 4) {
      int s = it * 8;
      int slot = s + pl;
      int hy = slot / HSTR;
      int hx = slot - hy * HSTR;
      int gy = ty0 - 1 + hy, gx = tx0 - 1 + hx;
      bool valid = (hx < 18) && ((unsigned)gy < HIMG) && ((unsigned)gx < WIMG);
      const void* src = valid
        ? (const void*)((const _Float16*)xTimg + (size_t)(gy * WIMG + gx) * 64
                        + ((j ^ (slot & 7)) << 3))
        : (const void*)((const char*)zpage + lane * 16);
      ld16_lds(src, (void*)(xs + s * 64));
    }
  }
  asm volatile("s_waitcnt vmcnt(0)" ::: "memory");
  __syncthreads();

  const int col = lane & 15;
  const int qrow = lane >> 4;            // 0..3 (PW / gram)
  const int rel = wid * 4 + (lane >> 4); // 0..15 (DW channel)
  const int row = (lane >> 1) & 7;       // DW image row
  const int half = lane & 1;             // DW 8-px half

  unsigned int qreg[4][4], kreg[4][4];   // [group][4 uint] = 8 px each

// PW16(P_,G_): pointwise MFMA, 16-ch group -> ys
#define PW16(P_, G_) do {                                                     \
    const _Float16* wp_ = wqb + ((((P_) * 64 + (G_) * 16 + col) << 6) + qrow * 8); \
    half8 wf0_ = *(const half8*)(wp_);                                        \
    half8 wf1_ = *(const half8*)(wp_ + 32);                                   \
    for (int mt = wid; mt < 15; mt += 4) {                                    \
      int px = mt * 16 + col;                                                 \
      half8 af0 = *(const half8*)(xs + px * 64 + (((qrow    ) ^ (px & 7)) << 3)); \
      half8 af1 = *(const half8*)(xs + px * 64 + (((4 + qrow) ^ (px & 7)) << 3)); \
      f32x4 a0 = {0,0,0,0};                                                   \
      a0 = __builtin_amdgcn_mfma_f32_16x16x32_f16(af0, wf0_, a0, 0, 0, 0);    \
      a0 = __builtin_amdgcn_mfma_f32_16x16x32_f16(af1, wf1_, a0, 0, 0, 0);    \
      int pxd = mt * 16 + qrow * 4;                                           \
      uint2 s0_ = {h2u(__floats2half2_rn(a0[0], a0[1])),                      \
                   h2u(__floats2half2_rn(a0[2], a0[3]))};                     \
      *(uint2*)(ys + col * YCH + pxd) = s0_;                                  \
    }                                                                         \
  } while (0)

// DW16(P_,G_): depthwise 3x3 for o=(G_)*16+rel, 8 px, from ys
#define DW16(P_, G_) do {                                                     \
    const int o_ = (G_) * 16 + rel;                                           \
    const _Float16* wdp_ = wdb + (((P_) * 64 + o_) << 4);                     \
    half8 wv_ = *(const half8*)wdp_;                                          \
    _Float16 w8_ = wdp_[8];                                                   \
    __half2 w2_[9];                                                           \
    _Pragma("unroll")                                                         \
    for (int j = 0; j < 8; ++j) w2_[j] = sp2(wv_[j]);                         \
    w2_[8] = sp2(w8_);                                                        \
    __half2 a_[4];                                                            \
    _Pragma("unroll")                                                         \
    for (int k2 = 0; k2 < 4; ++k2) a_[k2] = u2h(0u);                          \
    _Pragma("unroll")                                                         \
    for (int ky = 0; ky < 3; ++ky) {                                          \
      const _Float16* rp_ = ys + rel * YCH + (row + ky) * HSTR + half * 8;    \
      uint2 ra_ = *(const uint2*)rp_;                                         \
      uint2 rb_ = *(const uint2*)(rp_ + 4);                                   \
      unsigned int rc_ = *(const unsigned int*)(rp_ + 8);                     \
      unsigned int W_[5] = {ra_.x, ra_.y, rb_.x, rb_.y, rc_};                 \
      _Pragma("unroll")                                                       \
      for (int k2 = 0; k2 < 4; ++k2) {                                        \
        unsigned int M_ = (W_[k2] >> 16) | (W_[k2 + 1] << 16);                \
        a_[k2] = __hfma2(w2_[ky * 3 + 0], u2h(W_[k2]), a_[k2]);               \
        a_[k2] = __hfma2(w2_[ky * 3 + 1], u2h(M_), a_[k2]);                   \
        a_[k2] = __hfma2(w2_[ky * 3 + 2], u2h(W_[k2 + 1]), a_[k2]);           \
      }                                                                       \
    }                                                                         \
    if ((P_) == 0) {                                                          \
      _Pragma("unroll")                                                       \
      for (int k2 = 0; k2 < 4; ++k2) qreg[G_][k2] = h2u(a_[k2]);              \
    } else if ((P_) == 1) {                                                   \
      _Pragma("unroll")                                                       \
      for (int k2 = 0; k2 < 4; ++k2) kreg[G_][k2] = h2u(a_[k2]);              \
    } else {                                                                  \
      __half* vrow_ = (__half*)(vbuf                                          \
          + ((size_t)((br * 4 + b) * 64 + o_)) * NPIX                         \
          + (ty0 + row) * WIMG + tx0 + half * 8);                             \
      uint4 s_ = {h2u(a_[0]), h2u(a_[1]), h2u(a_[2]), h2u(a_[3])};            \
      *(uint4*)vrow_ = s_;                                                    \
    }                                                                         \
  } while (0)

  PW16(0, 0); __syncthreads(); DW16(0, 0); __syncthreads();
  PW16(0, 1); __syncthreads(); DW16(0, 1); __syncthreads();
  PW16(0, 2); __syncthreads(); DW16(0, 2); __syncthreads();
  PW16(0, 3); __syncthreads(); DW16(0, 3); __syncthreads();
  PW16(1, 0); __syncthreads(); DW16(1, 0); __syncthreads();
  PW16(1, 1); __syncthreads(); DW16(1, 1); __syncthreads();
  PW16(1, 2); __syncthreads(); DW16(1, 2); __syncthreads();
  PW16(1, 3); __syncthreads(); DW16(1, 3); __syncthreads();
  PW16(2, 0); __syncthreads(); DW16(2, 0); __syncthreads();
  PW16(2, 1); __syncthreads(); DW16(2, 1); __syncthreads();
  PW16(2, 2); __syncthreads(); DW16(2, 2); __syncthreads();
  PW16(2, 3); __syncthreads(); DW16(2, 3);

  // q,k regs -> xs region (all PW xs-reads done at the barrier after PW16(2,3))
  {
    _Float16* qsb = xs;
    _Float16* ksb = xs + 64 * 128;
    const int pb = row * 2 + half;
    #pragma unroll
    for (int g = 0; g < 4; ++g) {
      int ch = g * 16 + rel;
      uint4 q_ = {qreg[g][0], qreg[g][1], qreg[g][2], qreg[g][3]};
      uint4 k_ = {kreg[g][0], kreg[g][1], kreg[g][2], kreg[g][3]};
      *(uint4*)(qsb + qk_idx(ch, pb)) = q_;
      *(uint4*)(ksb + qk_idx(ch, pb)) = k_;
    }
  }
  __syncthreads();

  // ---- gram: qk + qq + kk diag head-tiles via MFMA, K=128 px ----
  {
    const _Float16* qsb = xs;
    const _Float16* ksb = xs + 64 * 128;
    f32x4 gqk = {0,0,0,0}, gqq = {0,0,0,0}, gkk = {0,0,0,0};
    int ch = wid * 16 + col;
    #pragma unroll
    for (int kc = 0; kc < 4; ++kc) {
      int pb = kc * 4 + qrow;
      half8 aq = *(const half8*)(qsb + qk_idx(ch, pb));
      half8 bk = *(const half8*)(ksb + qk_idx(ch, pb));
      gqk = __builtin_amdgcn_mfma_f32_16x16x32_f16(aq, bk, gqk, 0, 0, 0);
      gqq = __builtin_amdgcn_mfma_f32_16x16x32_f16(aq, aq, gqq, 0, 0, 0);
      gkk = __builtin_amdgcn_mfma_f32_16x16x32_f16(bk, bk, gkk, 0, 0, 0);
    }
    const int gb_off = (br * 4 + b);
    if (((lane >> 3) & 1) == (lane >> 5)) {
      float* gb = gram + gb_off * 512;
      int kch = ch;
      int qc0 = wid * 16 + qrow * 4;
      #pragma unroll
      for (int r = 0; r < 4; ++r) {
        int qch = qc0 + r;
        atomicAdd(&gb[(qch >> 3) * 64 + (qch & 7) * 8 + (kch & 7)], gqk[r]);
      }
    }
    if ((col >> 2) == qrow) {   // diagonal lanes
      atomicAdd(&sqq[gb_off * 64 + ch], gqq[lane & 3]);
      atomicAdd(&sqk[gb_off * 64 + ch], gkk[lane & 3]);
    }
  }
#undef PW16
#undef DW16
}

// softmax(G scaled) -> attn, Weff^T = (w_po @ blockdiag(attn))^T stored fp16 [o][c]
__global__ __launch_bounds__(64)
void k_attn(const float* __restrict__ gram, const float* __restrict__ sqq,
            const float* __restrict__ sqk,
            const float* __restrict__ wpo1, const float* __restrict__ wpo2,
            const float* __restrict__ t1, const float* __restrict__ t2,
            _Float16* __restrict__ wefft)
{
  const int br = blockIdx.x, b = blockIdx.y;
  const int t = threadIdx.x;
  __shared__ float attn[8][8][8];
  const float* gb = gram + (br * 4 + b) * 512;
  const float* sq = sqq + (br * 4 + b) * 64;
  const float* sk = sqk + (br * 4 + b) * 64;
  const float* tt = br ? t2 : t1;
  {
    int h = t >> 3, cq = t & 7;
    float ts = tt[h];
    float qn = fmaxf(sqrtf(sq[h * 8 + cq]), 1e-12f);
    float lg[8], m = -1e30f;
    #pragma unroll
    for (int d2 = 0; d2 < 8; ++d2) {
      float kn = fmaxf(sqrtf(sk[h * 8 + d2]), 1e-12f);
      lg[d2] = ts * gb[h * 64 + cq * 8 + d2] / (qn * kn);
      m = fmaxf(m, lg[d2]);
    }
    float s = 0.f;
    #pragma unroll
    for (int d2 = 0; d2 < 8; ++d2) { lg[d2] = expf(lg[d2] - m); s += lg[d2]; }
    float inv = 1.0f / s;
    #pragma unroll
    for (int d2 = 0; d2 < 8; ++d2) attn[h][cq][d2] = lg[d2] * inv;
  }
  __syncthreads();
  const float* wpo = br ? wpo2 : wpo1;
  _Float16* wt = wefft + (br * 4 + b) * 4096;
  for (int cp = 0; cp < 64; ++cp) {
    int hp = cp >> 3, ip = cp & 7;
    float acc = 0.f;
    #pragma unroll
    for (int j = 0; j < 8; ++j)
      acc += wpo[t * 64 + hp * 8 + j] * attn[hp][j][ip];
    wt[t * 64 + cp] = (_Float16)acc;   // [o][c]
  }
}

// out[b, obr*64+o2, px] = sum_c Weff[c][o2] * v[1-obr][b][c][px]  via MFMA
__global__ __launch_bounds__(256)
void k_out(const __half* __restrict__ vbuf, const _Float16* __restrict__ wefft,
           float* __restrict__ out)
{
  __shared__ __align__(16) _Float16 vs[64 * 128];   // 16384 B [c][px]
  __shared__ __align__(16) _Float16 vt[128 * 64];   // 16384 B [px][c] swizzled

  const int strip = blockIdx.x;        // 0..511, 128 px each
  const int obr = blockIdx.y, b = blockIdx.z;
  const int brv = 1 - obr;
  const int tid = threadIdx.x;
  const int lane = tid & 63;
  const int wid = tid >> 6;
  const int col = lane & 15;
  const int qrow = lane >> 4;

  const __half* vb = vbuf + ((size_t)(brv * 4 + b) * 64) * NPIX + strip * 128;

  for (int i = 0; i < 4; ++i) {
    int it = wid * 4 + i;
    const void* src = (const void*)((const _Float16*)vb
        + (size_t)(it * 4 + (lane >> 4)) * NPIX + (lane & 15) * 8);
    ld16_lds(src, (void*)(vs + it * 512));
  }
  asm volatile("s_waitcnt vmcnt(0)" ::: "memory");
  __syncthreads();

  {
    int px = tid & 127, cb = tid >> 7;
    #pragma unroll
    for (int j = 0; j < 4; ++j) {
      half8 h;
      #pragma unroll
      for (int e = 0; e < 8; ++e) h[e] = vs[(cb * 32 + j * 8 + e) * 128 + px];
      int chunk = cb * 4 + j;
      *(half8*)(vt + ((px * 8 + (chunk ^ (px & 7))) << 3)) = h;
    }
  }
  __syncthreads();

  const _Float16* wt = wefft + (obr * 4 + b) * 4096;
  half8 bf[2][4];
  #pragma unroll
  for (int nt = 0; nt < 4; ++nt)
    #pragma unroll
    for (int kc = 0; kc < 2; ++kc)
      bf[kc][nt] = *(const half8*)(wt + (nt * 16 + col) * 64 + kc * 32 + qrow * 8);

  float* ob = out + ((size_t)b * 128 + obr * 64) * NPIX + strip * 128;
  #pragma unroll
  for (int mi = 0; mi < 2; ++mi) {
    int mt = wid * 2 + mi;
    int px = mt * 16 + col;
    half8 af0 = *(const half8*)(vt + ((px * 8 + ((qrow    ) ^ (px & 7))) << 3));
    half8 af1 = *(const half8*)(vt + ((px * 8 + ((4 + qrow) ^ (px & 7))) << 3));
    f32x4 acc[4] = {{0,0,0,0},{0,0,0,0},{0,0,0,0},{0,0,0,0}};
    #pragma unroll
    for (int nt = 0; nt < 4; ++nt) {
      acc[nt] = __builtin_amdgcn_mfma_f32_16x16x32_f16(af0, bf[0][nt], acc[nt], 0, 0, 0);
      acc[nt] = __builtin_amdgcn_mfma_f32_16x16x32_f16(af1, bf[1][nt], acc[nt], 0, 0, 0);
    }
    int pxd = mt * 16 + qrow * 4;
    #pragma unroll
    for (int nt = 0; nt < 4; ++nt) {
      float4 s = {acc[nt][0], acc[nt][1], acc[nt][2], acc[nt][3]};
      *(float4*)(ob + (size_t)(nt * 16 + col) * NPIX + pxd) = s;
    }
  }
}

extern "C" void kernel_launch(void* const* d_in, const int* in_sizes, int n_in,
                              void* d_out, int out_size, void* d_ws, size_t ws_size,
                              hipStream_t stream) {
  const float* x     = (const float*)d_in[0];
  const float* wqkv1 = (const float*)d_in[1];
  const float* wqkv2 = (const float*)d_in[2];
  const float* wdw1  = (const float*)d_in[3];
  const float* wdw2  = (const float*)d_in[4];
  const float* wpo1  = (const float*)d_in[5];
  const float* wpo2  = (const float*)d_in[6];
  const float* t1    = (const float*)d_in[7];
  const float* t2    = (const float*)d_in[8];

  char* ws = (char*)d_ws;
  __half* vbuf = (__half*)ws;                     // 67,108,864 B
  float* gram  = (float*)(ws + 67108864);         // 4096 f32
  float* sqq   = gram + 4096;                     // 512
  float* sqk   = sqq + 512;                       // 512
  float* zpage = sqk + 512;                       // 1024 f32 (zeros for OOB DMA)
  _Float16* wqkvh = (_Float16*)(zpage + 1024);    // 2*12288 halves
  _Float16* wdwh  = wqkvh + 24576;                // 2*3072 halves
  _Float16* wefft = wdwh + 6144;                  // 2*4*4096 halves

  __half* xT = (__half*)d_out;   // xT in not-yet-written d_out

  k_prep<<<dim3(144), dim3(256), 0, stream>>>(wqkv1, wqkv2, wdw1, wdw2,
                                              gram, wqkvh, wdwh);
  k_xt<<<dim3(256, 2, 4), dim3(256), 0, stream>>>(x, xT);
  k_qkv<<<dim3(512, 2, 4), dim3(256), 0, stream>>>(xT, wqkvh, wdwh,
                                                   zpage, vbuf, gram, sqq, sqk);
  k_attn<<<dim3(2, 4), dim3(64), 0, stream>>>(gram, sqq, sqk, wpo1, wpo2, t1, t2, wefft);
  k_out<<<dim3(512, 2, 4), dim3(256), 0, stream>>>(vbuf, wefft, (float*)d_out);
}

// Round 17
// 220.818 us; speedup vs baseline: 1.2865x; 1.0911x over previous
//
#include <hip/hip_runtime.h>
#include <hip/hip_fp16.h>

#define NPIX 65536
#define WIMG 256
#define HIMG 256
#define TW 16
#define TH 8
#define HSTR 24      // halo row stride (halves): 10 rows x 24, 18 used per row
#define NSLOT 240
#define YCH 248      // ys per-channel stride (halves)

typedef __attribute__((ext_vector_type(8))) _Float16 half8;
typedef __attribute__((ext_vector_type(4))) float f32x4;

__device__ __forceinline__ unsigned int h2u(__half2 h) {
  union { __half2 h; unsigned int u; } c; c.h = h; return c.u;
}
__device__ __forceinline__ __half2 u2h(unsigned int u) {
  union { unsigned int u; __half2 h; } c; c.u = u; return c.h;
}
__device__ __forceinline__ __half2 sp2(_Float16 s) {
  union { _Float16 h[2]; __half2 v; } u; u.h[0] = s; u.h[1] = s; return u.v;
}
// q/k layout: [ch][px 0..127] swizzled; pxblk = px>>3
__device__ __forceinline__ int qk_idx(int ch, int pxblk) {
  return ch * 128 + ((pxblk ^ (ch & 7)) << 3);
}
__device__ __forceinline__ void ld16_lds(const void* g, void* l) {
  __builtin_amdgcn_global_load_lds(
      (const __attribute__((address_space(1))) unsigned int*)g,
      (__attribute__((address_space(3))) unsigned int*)l, 16, 0, 0);
}

// fused: zero accumulators (6144 f32) + weight fp16 pre-pack
__global__ __launch_bounds__(256)
void k_prep(const float* __restrict__ wq1, const float* __restrict__ wq2,
            const float* __restrict__ wd1, const float* __restrict__ wd2,
            float* __restrict__ zbuf,
            _Float16* __restrict__ wqh, _Float16* __restrict__ wdh) {
  int i = blockIdx.x * 256 + threadIdx.x;
  if (i < 6144) {
    zbuf[i] = 0.0f;
  } else {
    int j = i - 6144;
    if (j < 24576) {
      int br = j / 12288, r = j - br * 12288;
      wqh[j] = (_Float16)((br ? wq2 : wq1)[r]);
    } else {
      int k = j - 24576;
      int br = k / 3072, r = k - br * 3072;
      int o = r >> 4, t = r & 15;
      wdh[k] = (t < 9) ? (_Float16)((br ? wd2 : wd1)[o * 9 + t]) : (_Float16)0.0f;
    }
  }
}

// x f32 [b][128c][px] -> xT fp16 [b*2+br][px][c64]
__global__ __launch_bounds__(256)
void k_xt(const float* __restrict__ x, __half* __restrict__ xT) {
  __shared__ _Float16 tile[64 * 257];
  const int strip = blockIdx.x;
  const int br = blockIdx.y, b = blockIdx.z;
  const int tid = threadIdx.x;
  const float* xb = x + ((size_t)b * 128 + br * 64) * NPIX + strip * 256;
  #pragma unroll 8
  for (int c = 0; c < 64; ++c)
    tile[c * 257 + tid] = (_Float16)xb[(size_t)c * NPIX + tid];
  __syncthreads();
  __half* xo = xT + ((size_t)(b * 2 + br) * NPIX + strip * 256) * 64;
  const int j = tid & 7;
  #pragma unroll
  for (int i = 0; i < 8; ++i) {
    int p = (tid >> 3) + i * 32;
    half8 h;
    #pragma unroll
    for (int k = 0; k < 8; ++k) h[k] = tile[(j * 8 + k) * 257 + p];
    *(half8*)((_Float16*)xo + p * 64 + j * 8) = h;
  }
}

// r13 structure + double-buffered weight prefetch (sets A/B alternate per phase)
__global__ __launch_bounds__(256, 3)
void k_qkv(const __half* __restrict__ xT,
           const _Float16* __restrict__ wqh, const _Float16* __restrict__ wdh,
           const float* __restrict__ zpage,
           __half* __restrict__ vbuf, float* __restrict__ gram,
           float* __restrict__ sqq, float* __restrict__ sqk)
{
  __shared__ __align__(16) _Float16 xs[256 * 64];   // 32768 B; reused as q/k
  __shared__ __align__(16) _Float16 ys[32 * YCH];   // 15872 B

  const int tid = threadIdx.x;
  const int lane = tid & 63;
  const int wid = tid >> 6;
  const int tile = blockIdx.x;
  const int br = blockIdx.y;
  const int b = blockIdx.z;
  const int tx0 = (tile & 15) * TW;
  const int ty0 = (tile >> 4) * TH;

  const _Float16* wqb = wqh + br * 12288;
  const _Float16* wdb = wdh + br * 3072;
  const __half* xTimg = xT + (size_t)(b * 2 + br) * NPIX * 64;

  // ---- async DMA staging: 30 x 1KB, source-swizzled, LDS linear ----
  {
    const int j = lane & 7, pl = lane >> 3;
    for (int it = wid; it < 30; it += 4) {
      int s = it * 8;
      int slot = s + pl;
      int hy = slot / HSTR;
      int hx = slot - hy * HSTR;
      int gy = ty0 - 1 + hy, gx = tx0 - 1 + hx;
      bool valid = (hx < 18) && ((unsigned)gy < HIMG) && ((unsigned)gx < WIMG);
      const void* src = valid
        ? (const void*)((const _Float16*)xTimg + (size_t)(gy * WIMG + gx) * 64
                        + ((j ^ (slot & 7)) << 3))
        : (const void*)((const char*)zpage + lane * 16);
      ld16_lds(src, (void*)(xs + s * 64));
    }
  }
  asm volatile("s_waitcnt vmcnt(0)" ::: "memory");
  __syncthreads();

  const int col = lane & 15;
  const int qrow = lane >> 4;          // 0..3
  const int oo = tid >> 3;             // dw unit: 0..31
  const int row = tid & 7;

  unsigned int qreg[2][8], kreg[2][8]; // static-indexed (h,k2 unrolled)

// LOADW: fetch phase (P_,H_) weights into named register set
#define LOADW(P_, H_, F00, F01, F10, F11, WV, W8) do {                        \
    const _Float16* wp_ = wqb + ((((P_) * 64 + (H_) * 32 + col) << 6) + qrow * 8); \
    F00 = *(const half8*)(wp_);                                               \
    F10 = *(const half8*)(wp_ + 32);                                          \
    F01 = *(const half8*)(wp_ + 1024);                                        \
    F11 = *(const half8*)(wp_ + 1024 + 32);                                   \
    const _Float16* wdp_ = wdb + ((((P_) * 64 + (H_) * 32 + oo)) << 4);       \
    WV = *(const half8*)wdp_;                                                 \
    W8 = wdp_[8];                                                             \
} while (0)

// PHASE: PW via MFMA (weights F*) -> ys, barrier, DW 3x3 (weights WV/W8), barrier
#define PHASE(P_, H_, F00, F01, F10, F11, WV, W8) do {                        \
    for (int mt = wid; mt < 15; mt += 4) {                                    \
      int px = mt * 16 + col;                                                 \
      half8 af0 = *(const half8*)(xs + px * 64 + (((qrow    ) ^ (px & 7)) << 3)); \
      half8 af1 = *(const half8*)(xs + px * 64 + (((4 + qrow) ^ (px & 7)) << 3)); \
      f32x4 a0 = {0,0,0,0}, a1 = {0,0,0,0};                                   \
      a0 = __builtin_amdgcn_mfma_f32_16x16x32_f16(af0, F00, a0, 0, 0, 0);     \
      a0 = __builtin_amdgcn_mfma_f32_16x16x32_f16(af1, F10, a0, 0, 0, 0);     \
      a1 = __builtin_amdgcn_mfma_f32_16x16x32_f16(af0, F01, a1, 0, 0, 0);     \
      a1 = __builtin_amdgcn_mfma_f32_16x16x32_f16(af1, F11, a1, 0, 0, 0);     \
      int pxd = mt * 16 + qrow * 4;                                           \
      __half2* d0 = (__half2*)(ys + (col     ) * YCH + pxd);                  \
      __half2* d1 = (__half2*)(ys + (col + 16) * YCH + pxd);                  \
      d0[0] = __floats2half2_rn(a0[0], a0[1]);                                \
      d0[1] = __floats2half2_rn(a0[2], a0[3]);                                \
      d1[0] = __floats2half2_rn(a1[0], a1[1]);                                \
      d1[1] = __floats2half2_rn(a1[2], a1[3]);                                \
    }                                                                         \
    __syncthreads();                                                          \
    {                                                                         \
      const int o_ = (H_) * 32 + oo;                                          \
      __half2 w2_[9];                                                         \
      _Pragma("unroll")                                                       \
      for (int j = 0; j < 8; ++j) w2_[j] = sp2(WV[j]);                        \
      w2_[8] = sp2(W8);                                                       \
      __half2 a_[8];                                                          \
      _Pragma("unroll")                                                       \
      for (int k2 = 0; k2 < 8; ++k2) a_[k2] = u2h(0u);                        \
      _Pragma("unroll")                                                       \
      for (int ky = 0; ky < 3; ++ky) {                                        \
        const _Float16* rp_ = ys + oo * YCH + (row + ky) * HSTR;              \
        uint4 ra_ = *(const uint4*)rp_;                                       \
        uint4 rb_ = *(const uint4*)(rp_ + 8);                                 \
        unsigned int rc_ = *(const unsigned int*)(rp_ + 16);                  \
        unsigned int A_[9] = {ra_.x, ra_.y, ra_.z, ra_.w,                     \
                              rb_.x, rb_.y, rb_.z, rb_.w, rc_};               \
        _Pragma("unroll")                                                     \
        for (int k2 = 0; k2 < 8; ++k2) {                                      \
          unsigned int M_ = (A_[k2] >> 16) | (A_[k2 + 1] << 16);              \
          a_[k2] = __hfma2(w2_[ky * 3 + 0], u2h(A_[k2]), a_[k2]);             \
          a_[k2] = __hfma2(w2_[ky * 3 + 1], u2h(M_), a_[k2]);                 \
          a_[k2] = __hfma2(w2_[ky * 3 + 2], u2h(A_[k2 + 1]), a_[k2]);         \
        }                                                                     \
      }                                                                       \
      if ((P_) == 0) {                                                        \
        _Pragma("unroll")                                                     \
        for (int k2 = 0; k2 < 8; ++k2) qreg[H_][k2] = h2u(a_[k2]);            \
      } else if ((P_) == 1) {                                                 \
        _Pragma("unroll")                                                     \
        for (int k2 = 0; k2 < 8; ++k2) kreg[H_][k2] = h2u(a_[k2]);            \
      } else {                                                                \
        __half* vrow_ = (__half*)(vbuf                                        \
            + ((size_t)((br * 4 + b) * 64 + o_)) * NPIX                       \
            + (ty0 + row) * WIMG + tx0);                                      \
        uint4 s0_ = {h2u(a_[0]), h2u(a_[1]), h2u(a_[2]), h2u(a_[3])};         \
        uint4 s1_ = {h2u(a_[4]), h2u(a_[5]), h2u(a_[6]), h2u(a_[7])};         \
        *(uint4*)vrow_ = s0_;                                                 \
        *(uint4*)(vrow_ + 8) = s1_;                                           \
        if ((H_) == 1) {                                                      \
          _Float16* qsb_ = xs;                                                \
          _Float16* ksb_ = xs + 64 * 128;                                     \
          _Pragma("unroll")                                                   \
          for (int hh = 0; hh < 2; ++hh) {                                    \
            int ch = hh * 32 + oo;                                            \
            uint4 q0_ = {qreg[hh][0], qreg[hh][1], qreg[hh][2], qreg[hh][3]}; \
            uint4 q1_ = {qreg[hh][4], qreg[hh][5], qreg[hh][6], qreg[hh][7]}; \
            uint4 k0_ = {kreg[hh][0], kreg[hh][1], kreg[hh][2], kreg[hh][3]}; \
            uint4 k1_ = {kreg[hh][4], kreg[hh][5], kreg[hh][6], kreg[hh][7]}; \
            *(uint4*)(qsb_ + qk_idx(ch, 2 * row))     = q0_;                  \
            *(uint4*)(qsb_ + qk_idx(ch, 2 * row + 1)) = q1_;                  \
            *(uint4*)(ksb_ + qk_idx(ch, 2 * row))     = k0_;                  \
            *(uint4*)(ksb_ + qk_idx(ch, 2 * row + 1)) = k1_;                  \
          }                                                                   \
        }                                                                     \
      }                                                                       \
    }                                                                         \
    __syncthreads();                                                          \
} while (0)

  half8 Af00, Af01, Af10, Af11, Awv;
  half8 Bf00, Bf01, Bf10, Bf11, Bwv;
  _Float16 Aw8, Bw8;

  LOADW(0, 0, Af00, Af01, Af10, Af11, Awv, Aw8);
  LOADW(0, 1, Bf00, Bf01, Bf10, Bf11, Bwv, Bw8);
  PHASE(0, 0, Af00, Af01, Af10, Af11, Awv, Aw8);
  LOADW(1, 0, Af00, Af01, Af10, Af11, Awv, Aw8);
  PHASE(0, 1, Bf00, Bf01, Bf10, Bf11, Bwv, Bw8);
  LOADW(1, 1, Bf00, Bf01, Bf10, Bf11, Bwv, Bw8);
  PHASE(1, 0, Af00, Af01, Af10, Af11, Awv, Aw8);
  LOADW(2, 0, Af00, Af01, Af10, Af11, Awv, Aw8);
  PHASE(1, 1, Bf00, Bf01, Bf10, Bf11, Bwv, Bw8);
  LOADW(2, 1, Bf00, Bf01, Bf10, Bf11, Bwv, Bw8);
  PHASE(2, 0, Af00, Af01, Af10, Af11, Awv, Aw8);
  PHASE(2, 1, Bf00, Bf01, Bf10, Bf11, Bwv, Bw8);

  // ---- gram: qk + qq + kk diag head-tiles via MFMA, K=128 px ----
  {
    const _Float16* qsb = xs;
    const _Float16* ksb = xs + 64 * 128;
    f32x4 gqk = {0,0,0,0}, gqq = {0,0,0,0}, gkk = {0,0,0,0};
    int ch = wid * 16 + col;
    #pragma unroll
    for (int kc = 0; kc < 4; ++kc) {
      int pb = kc * 4 + qrow;
      half8 aq = *(const half8*)(qsb + qk_idx(ch, pb));
      half8 bk = *(const half8*)(ksb + qk_idx(ch, pb));
      gqk = __builtin_amdgcn_mfma_f32_16x16x32_f16(aq, bk, gqk, 0, 0, 0);
      gqq = __builtin_amdgcn_mfma_f32_16x16x32_f16(aq, aq, gqq, 0, 0, 0);
      gkk = __builtin_amdgcn_mfma_f32_16x16x32_f16(bk, bk, gkk, 0, 0, 0);
    }
    const int gb_off = (br * 4 + b);
    if (((lane >> 3) & 1) == (lane >> 5)) {
      float* gb = gram + gb_off * 512;
      int kch = ch;
      int qc0 = wid * 16 + qrow * 4;
      #pragma unroll
      for (int r = 0; r < 4; ++r) {
        int qch = qc0 + r;
        atomicAdd(&gb[(qch >> 3) * 64 + (qch & 7) * 8 + (kch & 7)], gqk[r]);
      }
    }
    if ((col >> 2) == qrow) {   // diagonal lanes
      atomicAdd(&sqq[gb_off * 64 + ch], gqq[lane & 3]);
      atomicAdd(&sqk[gb_off * 64 + ch], gkk[lane & 3]);
    }
  }
#undef LOADW
#undef PHASE
}

// softmax(G scaled) -> attn, Weff^T = (w_po @ blockdiag(attn))^T stored fp16 [o][c]
__global__ __launch_bounds__(64)
void k_attn(const float* __restrict__ gram, const float* __restrict__ sqq,
            const float* __restrict__ sqk,
            const float* __restrict__ wpo1, const float* __restrict__ wpo2,
            const float* __restrict__ t1, const float* __restrict__ t2,
            _Float16* __restrict__ wefft)
{
  const int br = blockIdx.x, b = blockIdx.y;
  const int t = threadIdx.x;
  __shared__ float attn[8][8][8];
  const float* gb = gram + (br * 4 + b) * 512;
  const float* sq = sqq + (br * 4 + b) * 64;
  const float* sk = sqk + (br * 4 + b) * 64;
  const float* tt = br ? t2 : t1;
  {
    int h = t >> 3, cq = t & 7;
    float ts = tt[h];
    float qn = fmaxf(sqrtf(sq[h * 8 + cq]), 1e-12f);
    float lg[8], m = -1e30f;
    #pragma unroll
    for (int d2 = 0; d2 < 8; ++d2) {
      float kn = fmaxf(sqrtf(sk[h * 8 + d2]), 1e-12f);
      lg[d2] = ts * gb[h * 64 + cq * 8 + d2] / (qn * kn);
      m = fmaxf(m, lg[d2]);
    }
    float s = 0.f;
    #pragma unroll
    for (int d2 = 0; d2 < 8; ++d2) { lg[d2] = expf(lg[d2] - m); s += lg[d2]; }
    float inv = 1.0f / s;
    #pragma unroll
    for (int d2 = 0; d2 < 8; ++d2) attn[h][cq][d2] = lg[d2] * inv;
  }
  __syncthreads();
  const float* wpo = br ? wpo2 : wpo1;
  _Float16* wt = wefft + (br * 4 + b) * 4096;
  for (int cp = 0; cp < 64; ++cp) {
    int hp = cp >> 3, ip = cp & 7;
    float acc = 0.f;
    #pragma unroll
    for (int j = 0; j < 8; ++j)
      acc += wpo[t * 64 + hp * 8 + j] * attn[hp][j][ip];
    wt[t * 64 + cp] = (_Float16)acc;   // [o][c]
  }
}

// out[b, obr*64+o2, px] = sum_c Weff[c][o2] * v[1-obr][b][c][px]  via MFMA
__global__ __launch_bounds__(256)
void k_out(const __half* __restrict__ vbuf, const _Float16* __restrict__ wefft,
           float* __restrict__ out)
{
  __shared__ __align__(16) _Float16 vs[64 * 128];   // 16384 B [c][px]
  __shared__ __align__(16) _Float16 vt[128 * 64];   // 16384 B [px][c] swizzled

  const int strip = blockIdx.x;        // 0..511, 128 px each
  const int obr = blockIdx.y, b = blockIdx.z;
  const int brv = 1 - obr;
  const int tid = threadIdx.x;
  const int lane = tid & 63;
  const int wid = tid >> 6;
  const int col = lane & 15;
  const int qrow = lane >> 4;

  const __half* vb = vbuf + ((size_t)(brv * 4 + b) * 64) * NPIX + strip * 128;

  for (int i = 0; i < 4; ++i) {
    int it = wid * 4 + i;
    const void* src = (const void*)((const _Float16*)vb
        + (size_t)(it * 4 + (lane >> 4)) * NPIX + (lane & 15) * 8);
    ld16_lds(src, (void*)(vs + it * 512));
  }
  asm volatile("s_waitcnt vmcnt(0)" ::: "memory");
  __syncthreads();

  {
    int px = tid & 127, cb = tid >> 7;
    #pragma unroll
    for (int j = 0; j < 4; ++j) {
      half8 h;
      #pragma unroll
      for (int e = 0; e < 8; ++e) h[e] = vs[(cb * 32 + j * 8 + e) * 128 + px];
      int chunk = cb * 4 + j;
      *(half8*)(vt + ((px * 8 + (chunk ^ (px & 7))) << 3)) = h;
    }
  }
  __syncthreads();

  const _Float16* wt = wefft + (obr * 4 + b) * 4096;
  half8 bf[2][4];
  #pragma unroll
  for (int nt = 0; nt < 4; ++nt)
    #pragma unroll
    for (int kc = 0; kc < 2; ++kc)
      bf[kc][nt] = *(const half8*)(wt + (nt * 16 + col) * 64 + kc * 32 + qrow * 8);

  float* ob = out + ((size_t)b * 128 + obr * 64) * NPIX + strip * 128;
  #pragma unroll
  for (int mi = 0; mi < 2; ++mi) {
    int mt = wid * 2 + mi;
    int px = mt * 16 + col;
    half8 af0 = *(const half8*)(vt + ((px * 8 + ((qrow    ) ^ (px & 7))) << 3));
    half8 af1 = *(const half8*)(vt + ((px * 8 + ((4 + qrow) ^ (px & 7))) << 3));
    f32x4 acc[4] = {{0,0,0,0},{0,0,0,0},{0,0,0,0},{0,0,0,0}};
    #pragma unroll
    for (int nt = 0; nt < 4; ++nt) {
      acc[nt] = __builtin_amdgcn_mfma_f32_16x16x32_f16(af0, bf[0][nt], acc[nt], 0, 0, 0);
      acc[nt] = __builtin_amdgcn_mfma_f32_16x16x32_f16(af1, bf[1][nt], acc[nt], 0, 0, 0);
    }
    int pxd = mt * 16 + qrow * 4;
    #pragma unroll
    for (int nt = 0; nt < 4; ++nt) {
      float4 s = {acc[nt][0], acc[nt][1], acc[nt][2], acc[nt][3]};
      *(float4*)(ob + (size_t)(nt * 16 + col) * NPIX + pxd) = s;
    }
  }
}

extern "C" void kernel_launch(void* const* d_in, const int* in_sizes, int n_in,
                              void* d_out, int out_size, void* d_ws, size_t ws_size,
                              hipStream_t stream) {
  const float* x     = (const float*)d_in[0];
  const float* wqkv1 = (const float*)d_in[1];
  const float* wqkv2 = (const float*)d_in[2];
  const float* wdw1  = (const float*)d_in[3];
  const float* wdw2  = (const float*)d_in[4];
  const float* wpo1  = (const float*)d_in[5];
  const float* wpo2  = (const float*)d_in[6];
  const float* t1    = (const float*)d_in[7];
  const float* t2    = (const float*)d_in[8];

  char* ws = (char*)d_ws;
  __half* vbuf = (__half*)ws;                     // 67,108,864 B
  float* gram  = (float*)(ws + 67108864);         // 4096 f32
  float* sqq   = gram + 4096;                     // 512
  float* sqk   = sqq + 512;                       // 512
  float* zpage = sqk + 512;                       // 1024 f32 (zeros for OOB DMA)
  _Float16* wqkvh = (_Float16*)(zpage + 1024);    // 2*12288 halves
  _Float16* wdwh  = wqkvh + 24576;                // 2*3072 halves
  _Float16* wefft = wdwh + 6144;                  // 2*4*4096 halves

  __half* xT = (__half*)d_out;   // xT in not-yet-written d_out

  k_prep<<<dim3(144), dim3(256), 0, stream>>>(wqkv1, wqkv2, wdw1, wdw2,
                                              gram, wqkvh, wdwh);
  k_xt<<<dim3(256, 2, 4), dim3(256), 0, stream>>>(x, xT);
  k_qkv<<<dim3(512, 2, 4), dim3(256), 0, stream>>>(xT, wqkvh, wdwh,
                                                   zpage, vbuf, gram, sqq, sqk);
  k_attn<<<dim3(2, 4), dim3(64), 0, stream>>>(gram, sqq, sqk, wpo1, wpo2, t1, t2, wefft);
  k_out<<<dim3(512, 2, 4), dim3(256), 0, stream>>>(vbuf, wefft, (float*)d_out);
}